// Round 4
// baseline (120.588 us; speedup 1.0000x reference)
//
#include <hip/hip_runtime.h>
#include <hip/hip_bf16.h>

#define KBINS 8
#define DDIM 2048
#define BROWS 4096
#define NPAR 25          // 3*K + 1
#define RPB 16           // rows per block
#define RCHUNK 8         // rows processed per register-resident chunk

__device__ __forceinline__ float fast_rcp(float a) {
    return __builtin_amdgcn_rcpf(a);   // ~1 ulp HW rcp; tolerance is bf16-level
}

__device__ __forceinline__ float fsigmoid(float t) {
    return fast_rcp(1.0f + __expf(-t));
}

// tab layout (d_ws), each row DDIM floats:
//   rows 0..8   = slopes[0..8]
//   rows 9..16  = x_knots[1..8]   (x_knots[0] == RMIN, not stored)
//   rows 17..24 = y_knots[1..8]   (y_knots[0] == RMIN, not stored)
__global__ __launch_bounds__(128) void normalize_kernel(
        const float* __restrict__ params, float* __restrict__ tab) {
    const int d = blockIdx.x * 128 + (int)threadIdx.x;
    const float RMIN = -5.0f, RMAX = 5.0f;
    const float MIN_BIN = 1e-3f, MIN_SLOPE = 1e-3f, MAX_SLOPE = 10.0f;
    const float remaining = (RMAX - RMIN) - KBINS * MIN_BIN;  // 9.992

    const float* p = params + d * NPAR;
    float pr[NPAR];
#pragma unroll
    for (int i = 0; i < NPAR; ++i) pr[i] = p[i];   // 25 independent loads

    float ws[KBINS], hs[KBINS];
    float wsum = 0.0f, hsum = 0.0f;
#pragma unroll
    for (int k = 0; k < KBINS; ++k) { ws[k] = fsigmoid(pr[k]); wsum += ws[k]; }
#pragma unroll
    for (int k = 0; k < KBINS; ++k) { hs[k] = fsigmoid(pr[KBINS + k]); hsum += hs[k]; }

    const float wscale = remaining * fast_rcp(wsum);
    const float hscale = remaining * fast_rcp(hsum);

#pragma unroll
    for (int k = 0; k <= KBINS; ++k)
        tab[k * DDIM + d] = MIN_SLOPE + (MAX_SLOPE - MIN_SLOPE) * fsigmoid(pr[2 * KBINS + k]);

    float cx = RMIN, cy = RMIN;
#pragma unroll
    for (int k = 0; k < KBINS; ++k) {
        cx += MIN_BIN + ws[k] * wscale;
        cy += MIN_BIN + hs[k] * hscale;
        tab[(9 + k) * DDIM + d] = cx;
        tab[(17 + k) * DDIM + d] = cy;
    }
}

// Main kernel: block = 256 threads = one 256-column chunk x 16 rows.
// Tables for the chunk live in LDS [25][256]; gather address word-index
// = bin*256 + tid  ->  bank = tid%32  -> conflict-free (2-way wave64 aliasing is free).
__global__ __launch_bounds__(256, 6) void rqs_kernel(
        const float* __restrict__ x_in, const float* __restrict__ tab,
        float* __restrict__ y_out, float* __restrict__ logdet) {
    __shared__ float lt[25 * 256];

    const int tid = (int)threadIdx.x;
    const int c0 = (blockIdx.x & 7) * 256;
    const int d = c0 + tid;
    const int b0 = (int)(blockIdx.x >> 3) * RPB;

    const float RMIN = -5.0f, RMAX = 5.0f;

#pragma unroll
    for (int r = 0; r < 25; ++r) lt[r * 256 + tid] = tab[r * DDIM + c0 + tid];
    __syncthreads();

    float xkr[7];                       // interior knots xk[1..7] for binning
#pragma unroll
    for (int j = 0; j < 7; ++j) xkr[j] = lt[(9 + j) * 256 + tid];
    const float s0 = lt[0 * 256 + tid];
    const float sK = lt[8 * 256 + tid];
    const float log_s0 = __logf(s0), log_sK = __logf(sK);

    const float* ltp = lt + tid;

    for (int rc = 0; rc < RPB; rc += RCHUNK) {
        float xv[RCHUNK];
#pragma unroll
        for (int r = 0; r < RCHUNK; ++r)
            xv[r] = x_in[(size_t)(b0 + rc + r) * DDIM + d];

        float ldv[RCHUNK];
#pragma unroll
        for (int r = 0; r < RCHUNK; ++r) {
            const float x = xv[r];
            int bin = 0;
#pragma unroll
            for (int j = 0; j < 7; ++j) bin += (xkr[j] <= x) ? 1 : 0;

            const float* base = ltp + bin * 256;
            const float dk   = base[0];          // sl[bin]
            const float dk1  = base[256];        // sl[bin+1]
            float x_k        = base[8 * 256];    // xk[bin]   (garbage if bin==0)
            const float x_k1 = base[9 * 256];    // xk[bin+1]
            float y_k        = base[16 * 256];   // yk[bin]   (garbage if bin==0)
            const float y_k1 = base[17 * 256];   // yk[bin+1]
            const bool bz = (bin == 0);
            x_k = bz ? RMIN : x_k;
            y_k = bz ? RMIN : y_k;

            const float w = x_k1 - x_k;
            const float h = y_k1 - y_k;
            const float inv_w = fast_rcp(w);
            const float xi  = (x - x_k) * inv_w;
            const float s   = h * inv_w;
            const float xi1 = 1.0f - xi;
            const float xx  = xi * xi1;
            const float xi2 = xi * xi;

            const float num = fmaf(s, xi2, dk * xx);
            const float den = fmaf(fmaf(-2.0f, s, dk1 + dk), xx, s);
            const float inv_den = fast_rcp(den);

            const float y_sp = fmaf(h * num, inv_den, y_k);
            const float inner = fmaf(dk1, xi2, fmaf(s + s, xx, dk * (xi1 * xi1)));
            const float t = s * inv_den;

            const bool below = x <= RMIN;
            const bool above = x >= RMAX;
            float y  = below ? fmaf(x - RMIN, s0, RMIN)
                     : above ? fmaf(x - RMAX, sK, RMAX) : y_sp;
            float ld = below ? log_s0
                     : above ? log_sK : __logf(t * t * inner);

            y_out[(size_t)(b0 + rc + r) * DDIM + d] = y;
            ldv[r] = ld;
        }

        // 8 independent butterfly chains, interleaved (latency-pipelined)
#pragma unroll
        for (int off = 32; off > 0; off >>= 1) {
#pragma unroll
            for (int r = 0; r < RCHUNK; ++r)
                ldv[r] += __shfl_down(ldv[r], off);
        }
        if ((tid & 63) == 0) {
#pragma unroll
            for (int r = 0; r < RCHUNK; ++r)
                atomicAdd(&logdet[b0 + rc + r], ldv[r]);
        }
    }
}

extern "C" void kernel_launch(void* const* d_in, const int* in_sizes, int n_in,
                              void* d_out, int out_size, void* d_ws, size_t ws_size,
                              hipStream_t stream) {
    const float* x = (const float*)d_in[0];
    const float* params = (const float*)d_in[1];
    float* out = (float*)d_out;
    float* y_out = out;                          // B*D floats
    float* logdet = out + (size_t)BROWS * DDIM;  // B floats
    float* tab = (float*)d_ws;                   // 25*D floats = 200 KiB

    hipMemsetAsync(logdet, 0, BROWS * sizeof(float), stream);

    normalize_kernel<<<DDIM / 128, 128, 0, stream>>>(params, tab);

    const int grid = 8 * (BROWS / RPB);          // 2048 blocks
    rqs_kernel<<<grid, 256, 0, stream>>>(x, tab, y_out, logdet);
}

// Round 5
// 118.270 us; speedup vs baseline: 1.0196x; 1.0196x over previous
//
#include <hip/hip_runtime.h>
#include <hip/hip_bf16.h>

#define KBINS 8
#define DDIM 2048
#define BROWS 4096
#define NPAR 25          // 3*K + 1
#define RPB 16           // rows per block
#define RCHUNK 4         // rows per software-pipelined chunk
#define NCHUNK (RPB / RCHUNK)

__device__ __forceinline__ float fast_rcp(float a) {
    return __builtin_amdgcn_rcpf(a);   // ~1 ulp HW rcp; tolerance is bf16-level
}

__device__ __forceinline__ float fsigmoid(float t) {
    return fast_rcp(1.0f + __expf(-t));
}

// DPP-assisted add: v + dpp_move(v). out-of-bounds / masked-off lanes
// contribute old=0. All on the VALU pipe (no LDS traffic).
template<int CTRL, int ROWMASK>
__device__ __forceinline__ float dpp_add(float v) {
    int r = __builtin_amdgcn_update_dpp(0, __float_as_int(v), CTRL, ROWMASK, 0xf, false);
    return v + __int_as_float(r);
}

// full wave64 sum -> lane 63 (row_shr 1/2/4/8, bcast15 rows{1,3}, bcast31 rows{2,3})
__device__ __forceinline__ float wave_sum64(float v) {
    v = dpp_add<0x111, 0xf>(v);
    v = dpp_add<0x112, 0xf>(v);
    v = dpp_add<0x114, 0xf>(v);
    v = dpp_add<0x118, 0xf>(v);
    v = dpp_add<0x142, 0xa>(v);   // row_bcast:15
    v = dpp_add<0x143, 0xc>(v);   // row_bcast:31
    return v;
}

// tab layout (d_ws), each row DDIM floats:
//   rows 0..8   = slopes[0..8]
//   rows 9..16  = x_knots[1..8]   (x_knots[0] == RMIN, not stored)
//   rows 17..24 = y_knots[1..8]   (y_knots[0] == RMIN, not stored)
__global__ __launch_bounds__(128) void normalize_kernel(
        const float* __restrict__ params, float* __restrict__ tab) {
    const int d = blockIdx.x * 128 + (int)threadIdx.x;
    const float RMIN = -5.0f, RMAX = 5.0f;
    const float MIN_BIN = 1e-3f, MIN_SLOPE = 1e-3f, MAX_SLOPE = 10.0f;
    const float remaining = (RMAX - RMIN) - KBINS * MIN_BIN;  // 9.992

    const float* p = params + d * NPAR;
    float pr[NPAR];
#pragma unroll
    for (int i = 0; i < NPAR; ++i) pr[i] = p[i];

    float ws[KBINS], hs[KBINS];
    float wsum = 0.0f, hsum = 0.0f;
#pragma unroll
    for (int k = 0; k < KBINS; ++k) { ws[k] = fsigmoid(pr[k]); wsum += ws[k]; }
#pragma unroll
    for (int k = 0; k < KBINS; ++k) { hs[k] = fsigmoid(pr[KBINS + k]); hsum += hs[k]; }

    const float wscale = remaining * fast_rcp(wsum);
    const float hscale = remaining * fast_rcp(hsum);

#pragma unroll
    for (int k = 0; k <= KBINS; ++k)
        tab[k * DDIM + d] = MIN_SLOPE + (MAX_SLOPE - MIN_SLOPE) * fsigmoid(pr[2 * KBINS + k]);

    float cx = RMIN, cy = RMIN;
#pragma unroll
    for (int k = 0; k < KBINS; ++k) {
        cx += MIN_BIN + ws[k] * wscale;
        cy += MIN_BIN + hs[k] * hscale;
        tab[(9 + k) * DDIM + d] = cx;
        tab[(17 + k) * DDIM + d] = cy;
    }
}

// Main kernel: zero LDS, register-resident tables, cndmask bin-select,
// DPP wave reduction. VGPR target <=64 -> 8 waves/SIMD, grid 2048x4 waves
// = exactly device-resident.
__global__ __launch_bounds__(256, 8) void rqs_kernel(
        const float* __restrict__ x_in, const float* __restrict__ tab,
        float* __restrict__ y_out, float* __restrict__ logdet) {
    const int tid = (int)threadIdx.x;
    const int d = (blockIdx.x & 7) * 256 + tid;
    const int b0 = (int)(blockIdx.x >> 3) * RPB;

    const float RMIN = -5.0f, RMAX = 5.0f;

    // 25 coalesced loads (tab is L2-resident: 200 KB)
    float sl[9], xk[9], yk[9];
#pragma unroll
    for (int k = 0; k < 9; ++k) sl[k] = tab[k * DDIM + d];
#pragma unroll
    for (int k = 1; k < 9; ++k) xk[k] = tab[(8 + k) * DDIM + d];
#pragma unroll
    for (int k = 1; k < 9; ++k) yk[k] = tab[(16 + k) * DDIM + d];

    const float log_s0 = __logf(sl[0]);
    const float log_sK = __logf(sl[8]);

    float xv[RCHUNK], xn[RCHUNK];
#pragma unroll
    for (int r = 0; r < RCHUNK; ++r)
        xv[r] = x_in[(size_t)(b0 + r) * DDIM + d];

#pragma unroll 1
    for (int rc = 0; rc < NCHUNK; ++rc) {
        // prefetch next chunk's x while computing this one
        if (rc + 1 < NCHUNK) {
#pragma unroll
            for (int r = 0; r < RCHUNK; ++r)
                xn[r] = x_in[(size_t)(b0 + (rc + 1) * RCHUNK + r) * DDIM + d];
        }

        float ldv[RCHUNK];
#pragma unroll
        for (int r = 0; r < RCHUNK; ++r) {
            const float x = xv[r];

            // chained select: after step j, state = bin>=j values
            float x_k = RMIN, x_k1 = xk[1];
            float y_k = RMIN, y_k1 = yk[1];
            float dk = sl[0], dk1 = sl[1];
#pragma unroll
            for (int j = 1; j < 8; ++j) {
                const bool c = xk[j] <= x;
                x_k  = c ? xk[j]     : x_k;
                x_k1 = c ? xk[j + 1] : x_k1;
                y_k  = c ? yk[j]     : y_k;
                y_k1 = c ? yk[j + 1] : y_k1;
                dk   = c ? sl[j]     : dk;
                dk1  = c ? sl[j + 1] : dk1;
            }

            const float w = x_k1 - x_k;
            const float h = y_k1 - y_k;
            const float inv_w = fast_rcp(w);
            const float xi  = (x - x_k) * inv_w;
            const float s   = h * inv_w;
            const float xi1 = 1.0f - xi;
            const float xx  = xi * xi1;
            const float xi2 = xi * xi;

            const float num = fmaf(s, xi2, dk * xx);
            const float den = fmaf(fmaf(-2.0f, s, dk1 + dk), xx, s);
            const float inv_den = fast_rcp(den);

            const float y_sp = fmaf(h * num, inv_den, y_k);
            const float inner = fmaf(dk1, xi2, fmaf(s + s, xx, dk * (xi1 * xi1)));
            const float t = s * inv_den;

            const bool below = x <= RMIN;
            const bool above = x >= RMAX;
            float y  = below ? fmaf(x - RMIN, sl[0], RMIN)
                     : above ? fmaf(x - RMAX, sl[8], RMAX) : y_sp;
            float ld = below ? log_s0
                     : above ? log_sK : __logf(t * t * inner);

            y_out[(size_t)(b0 + rc * RCHUNK + r) * DDIM + d] = y;
            ldv[r] = ld;
        }

        // 4 independent DPP reduce chains (VALU pipe), 1 atomic/row/wave
#pragma unroll
        for (int r = 0; r < RCHUNK; ++r) ldv[r] = wave_sum64(ldv[r]);
        if ((tid & 63) == 63) {
#pragma unroll
            for (int r = 0; r < RCHUNK; ++r)
                atomicAdd(&logdet[b0 + rc * RCHUNK + r], ldv[r]);
        }

#pragma unroll
        for (int r = 0; r < RCHUNK; ++r) xv[r] = xn[r];
    }
}

extern "C" void kernel_launch(void* const* d_in, const int* in_sizes, int n_in,
                              void* d_out, int out_size, void* d_ws, size_t ws_size,
                              hipStream_t stream) {
    const float* x = (const float*)d_in[0];
    const float* params = (const float*)d_in[1];
    float* out = (float*)d_out;
    float* y_out = out;                          // B*D floats
    float* logdet = out + (size_t)BROWS * DDIM;  // B floats
    float* tab = (float*)d_ws;                   // 25*D floats = 200 KiB

    hipMemsetAsync(logdet, 0, BROWS * sizeof(float), stream);

    normalize_kernel<<<DDIM / 128, 128, 0, stream>>>(params, tab);

    const int grid = 8 * (BROWS / RPB);          // 2048 blocks
    rqs_kernel<<<grid, 256, 0, stream>>>(x, tab, y_out, logdet);
}

// Round 6
// 109.114 us; speedup vs baseline: 1.1052x; 1.0839x over previous
//
#include <hip/hip_runtime.h>
#include <hip/hip_bf16.h>

#define KBINS 8
#define DDIM 2048
#define BROWS 4096
#define NPAR 25          // 3*K + 1
#define RPB 32           // rows per block
#define RCHUNK 4         // rows per software-pipelined chunk
#define NCHUNK (RPB / RCHUNK)

__device__ __forceinline__ float fast_rcp(float a) {
    return __builtin_amdgcn_rcpf(a);   // ~1 ulp HW rcp; tolerance is bf16-level
}

__device__ __forceinline__ float fsigmoid(float t) {
    return fast_rcp(1.0f + __expf(-t));
}

// DPP-assisted add on the VALU pipe (no LDS traffic).
template<int CTRL, int ROWMASK>
__device__ __forceinline__ float dpp_add(float v) {
    int r = __builtin_amdgcn_update_dpp(0, __float_as_int(v), CTRL, ROWMASK, 0xf, false);
    return v + __int_as_float(r);
}

// full wave64 sum -> lane 63 (row_shr 1/2/4/8, bcast15 rows{1,3}, bcast31 rows{2,3})
__device__ __forceinline__ float wave_sum64(float v) {
    v = dpp_add<0x111, 0xf>(v);
    v = dpp_add<0x112, 0xf>(v);
    v = dpp_add<0x114, 0xf>(v);
    v = dpp_add<0x118, 0xf>(v);
    v = dpp_add<0x142, 0xa>(v);   // row_bcast:15
    v = dpp_add<0x143, 0xc>(v);   // row_bcast:31
    return v;
}

// tab layout (d_ws), each row DDIM floats:
//   rows 0..8   = slopes[0..8]
//   rows 9..16  = x_knots[1..8]   (x_knots[0] == RMIN, not stored)
//   rows 17..24 = y_knots[1..8]   (y_knots[0] == RMIN, not stored)
__global__ __launch_bounds__(128) void normalize_kernel(
        const float* __restrict__ params, float* __restrict__ tab) {
    const int d = blockIdx.x * 128 + (int)threadIdx.x;
    const float RMIN = -5.0f, RMAX = 5.0f;
    const float MIN_BIN = 1e-3f, MIN_SLOPE = 1e-3f, MAX_SLOPE = 10.0f;
    const float remaining = (RMAX - RMIN) - KBINS * MIN_BIN;  // 9.992

    const float* p = params + d * NPAR;
    float pr[NPAR];
#pragma unroll
    for (int i = 0; i < NPAR; ++i) pr[i] = p[i];

    float ws[KBINS], hs[KBINS];
    float wsum = 0.0f, hsum = 0.0f;
#pragma unroll
    for (int k = 0; k < KBINS; ++k) { ws[k] = fsigmoid(pr[k]); wsum += ws[k]; }
#pragma unroll
    for (int k = 0; k < KBINS; ++k) { hs[k] = fsigmoid(pr[KBINS + k]); hsum += hs[k]; }

    const float wscale = remaining * fast_rcp(wsum);
    const float hscale = remaining * fast_rcp(hsum);

#pragma unroll
    for (int k = 0; k <= KBINS; ++k)
        tab[k * DDIM + d] = MIN_SLOPE + (MAX_SLOPE - MIN_SLOPE) * fsigmoid(pr[2 * KBINS + k]);

    float cx = RMIN, cy = RMIN;
#pragma unroll
    for (int k = 0; k < KBINS; ++k) {
        cx += MIN_BIN + ws[k] * wscale;
        cy += MIN_BIN + hs[k] * hscale;
        tab[(9 + k) * DDIM + d] = cx;
        tab[(17 + k) * DDIM + d] = cy;
    }
}

// Main kernel: zero LDS, register-resident tables, cndmask bin-select,
// DPP wave reduction. launch_bounds(256,4) -> <=128 VGPR budget so the
// 27 table values STAY in registers (VGPR=32 builds rematerialize them
// from L2 every row -> the 45us attractor of R1-R5).
__global__ __launch_bounds__(256, 4) void rqs_kernel(
        const float* __restrict__ x_in, const float* __restrict__ tab,
        float* __restrict__ y_out, float* __restrict__ logdet) {
    const int tid = (int)threadIdx.x;
    const int d = (blockIdx.x & 7) * 256 + tid;
    const int b0 = (int)(blockIdx.x >> 3) * RPB;

    const float RMIN = -5.0f, RMAX = 5.0f;

    // 25 coalesced loads (tab is L2-resident: 200 KB); keep in registers.
    float sl[9], xk[9], yk[9];
#pragma unroll
    for (int k = 0; k < 9; ++k) sl[k] = tab[k * DDIM + d];
#pragma unroll
    for (int k = 1; k < 9; ++k) xk[k] = tab[(8 + k) * DDIM + d];
#pragma unroll
    for (int k = 1; k < 9; ++k) yk[k] = tab[(16 + k) * DDIM + d];

    const float log_s0 = __logf(sl[0]);
    const float log_sK = __logf(sl[8]);

    const float* xp = x_in + (size_t)b0 * DDIM + d;
    float* yp = y_out + (size_t)b0 * DDIM + d;

    float xv[RCHUNK], xn[RCHUNK];
#pragma unroll
    for (int r = 0; r < RCHUNK; ++r) xv[r] = xp[(size_t)r * DDIM];

#pragma unroll 1
    for (int rc = 0; rc < NCHUNK; ++rc) {
        // prefetch next chunk's x while computing this one
        if (rc + 1 < NCHUNK) {
#pragma unroll
            for (int r = 0; r < RCHUNK; ++r)
                xn[r] = xp[(size_t)((rc + 1) * RCHUNK + r) * DDIM];
        }

        float ldv[RCHUNK];
#pragma unroll
        for (int r = 0; r < RCHUNK; ++r) {
            const float x = xv[r];

            // chained select: after step j, state = values for bin>=j
            float x_k = RMIN, x_k1 = xk[1];
            float y_k = RMIN, y_k1 = yk[1];
            float dk = sl[0], dk1 = sl[1];
#pragma unroll
            for (int j = 1; j < 8; ++j) {
                const bool c = xk[j] <= x;
                x_k  = c ? xk[j]     : x_k;
                x_k1 = c ? xk[j + 1] : x_k1;
                y_k  = c ? yk[j]     : y_k;
                y_k1 = c ? yk[j + 1] : y_k1;
                dk   = c ? sl[j]     : dk;
                dk1  = c ? sl[j + 1] : dk1;
            }

            const float w = x_k1 - x_k;
            const float h = y_k1 - y_k;
            const float inv_w = fast_rcp(w);
            const float xi  = (x - x_k) * inv_w;
            const float s   = h * inv_w;
            const float xi1 = 1.0f - xi;
            const float xx  = xi * xi1;
            const float xi2 = xi * xi;

            const float num = fmaf(s, xi2, dk * xx);
            const float den = fmaf(fmaf(-2.0f, s, dk1 + dk), xx, s);
            const float inv_den = fast_rcp(den);

            const float y_sp = fmaf(h * num, inv_den, y_k);
            const float inner = fmaf(dk1, xi2, fmaf(s + s, xx, dk * (xi1 * xi1)));
            const float t = s * inv_den;

            const bool below = x <= RMIN;
            const bool above = x >= RMAX;
            float y  = below ? fmaf(x - RMIN, sl[0], RMIN)
                     : above ? fmaf(x - RMAX, sl[8], RMAX) : y_sp;
            float ld = below ? log_s0
                     : above ? log_sK : __logf(t * t * inner);

            yp[(size_t)(rc * RCHUNK + r) * DDIM] = y;
            ldv[r] = ld;
        }

        // 4 independent DPP reduce chains (VALU pipe), 1 atomic/row/wave
#pragma unroll
        for (int r = 0; r < RCHUNK; ++r) ldv[r] = wave_sum64(ldv[r]);
        if ((tid & 63) == 63) {
#pragma unroll
            for (int r = 0; r < RCHUNK; ++r)
                atomicAdd(&logdet[b0 + rc * RCHUNK + r], ldv[r]);
        }

#pragma unroll
        for (int r = 0; r < RCHUNK; ++r) xv[r] = xn[r];
    }
}

extern "C" void kernel_launch(void* const* d_in, const int* in_sizes, int n_in,
                              void* d_out, int out_size, void* d_ws, size_t ws_size,
                              hipStream_t stream) {
    const float* x = (const float*)d_in[0];
    const float* params = (const float*)d_in[1];
    float* out = (float*)d_out;
    float* y_out = out;                          // B*D floats
    float* logdet = out + (size_t)BROWS * DDIM;  // B floats
    float* tab = (float*)d_ws;                   // 25*D floats = 200 KiB

    hipMemsetAsync(logdet, 0, BROWS * sizeof(float), stream);

    normalize_kernel<<<DDIM / 128, 128, 0, stream>>>(params, tab);

    const int grid = 8 * (BROWS / RPB);          // 1024 blocks = one resident generation
    rqs_kernel<<<grid, 256, 0, stream>>>(x, tab, y_out, logdet);
}

// Round 7
// 107.442 us; speedup vs baseline: 1.1223x; 1.0156x over previous
//
#include <hip/hip_runtime.h>
#include <hip/hip_bf16.h>

#define KBINS 8
#define DDIM 2048
#define BROWS 4096
#define NPAR 25          // 3*K + 1
#define RPB 32           // rows per block
#define RCHUNK 8         // rows per software-pipelined chunk
#define NCHUNK (RPB / RCHUNK)

__device__ __forceinline__ float fast_rcp(float a) {
    return __builtin_amdgcn_rcpf(a);   // ~1 ulp HW rcp; tolerance is bf16-level
}

__device__ __forceinline__ float fsigmoid(float t) {
    return fast_rcp(1.0f + __expf(-t));
}

// DPP-assisted add on the VALU pipe (no LDS traffic).
template<int CTRL, int ROWMASK>
__device__ __forceinline__ float dpp_add(float v) {
    int r = __builtin_amdgcn_update_dpp(0, __float_as_int(v), CTRL, ROWMASK, 0xf, false);
    return v + __int_as_float(r);
}

// full wave64 sum -> lane 63 (row_shr 1/2/4/8, bcast15 rows{1,3}, bcast31 rows{2,3})
__device__ __forceinline__ float wave_sum64(float v) {
    v = dpp_add<0x111, 0xf>(v);
    v = dpp_add<0x112, 0xf>(v);
    v = dpp_add<0x114, 0xf>(v);
    v = dpp_add<0x118, 0xf>(v);
    v = dpp_add<0x142, 0xa>(v);   // row_bcast:15
    v = dpp_add<0x143, 0xc>(v);   // row_bcast:31
    return v;
}

// tab layout (d_ws), each row DDIM floats:
//   rows 0..8   = slopes[0..8]
//   rows 9..16  = x_knots[1..8]   (x_knots[0] == RMIN, not stored)
//   rows 17..24 = y_knots[1..8]   (y_knots[0] == RMIN, not stored)
// Also zeroes logdet (fused; rqs atomics accumulate on top, stream-ordered).
__global__ __launch_bounds__(128) void normalize_kernel(
        const float* __restrict__ params, float* __restrict__ tab,
        float* __restrict__ logdet) {
    const int tid = (int)threadIdx.x;
    const int d0 = (int)blockIdx.x * 128;
    const int d = d0 + tid;

    // zero logdet: 16 blocks x 128 threads, 2 elems each
    logdet[(int)blockIdx.x * 128 + tid] = 0.0f;
    logdet[2048 + (int)blockIdx.x * 128 + tid] = 0.0f;

    // stage this block's params slice coalesced: 128 cols x 25 = 3200 floats
    __shared__ float sp[128 * NPAR];
#pragma unroll
    for (int i = 0; i < NPAR; ++i)
        sp[i * 128 + tid] = params[(size_t)d0 * NPAR + i * 128 + tid];
    __syncthreads();
    // per-thread params at sp[tid*25 + i]; stride 25 is coprime with 32 banks
    const float* p = sp + tid * NPAR;

    const float RMIN = -5.0f, RMAX = 5.0f;
    const float MIN_BIN = 1e-3f, MIN_SLOPE = 1e-3f, MAX_SLOPE = 10.0f;
    const float remaining = (RMAX - RMIN) - KBINS * MIN_BIN;  // 9.992

    float ws[KBINS], hs[KBINS];
    float wsum = 0.0f, hsum = 0.0f;
#pragma unroll
    for (int k = 0; k < KBINS; ++k) { ws[k] = fsigmoid(p[k]); wsum += ws[k]; }
#pragma unroll
    for (int k = 0; k < KBINS; ++k) { hs[k] = fsigmoid(p[KBINS + k]); hsum += hs[k]; }

    const float wscale = remaining * fast_rcp(wsum);
    const float hscale = remaining * fast_rcp(hsum);

#pragma unroll
    for (int k = 0; k <= KBINS; ++k)
        tab[k * DDIM + d] = MIN_SLOPE + (MAX_SLOPE - MIN_SLOPE) * fsigmoid(p[2 * KBINS + k]);

    float cx = RMIN, cy = RMIN;
#pragma unroll
    for (int k = 0; k < KBINS; ++k) {
        cx += MIN_BIN + ws[k] * wscale;
        cy += MIN_BIN + hs[k] * hscale;
        tab[(9 + k) * DDIM + d] = cx;
        tab[(17 + k) * DDIM + d] = cy;
    }
}

// Main kernel: zero LDS, register-resident tables, cndmask bin-select,
// DPP wave reduction. launch_bounds(256,4) -> <=128 VGPR budget so the
// 27 table values STAY in registers (the 32-VGPR builds of R1-R5
// rematerialized/spilled them -> ~39MB of scratch writeback, 45us attractor).
__global__ __launch_bounds__(256, 4) void rqs_kernel(
        const float* __restrict__ x_in, const float* __restrict__ tab,
        float* __restrict__ y_out, float* __restrict__ logdet) {
    const int tid = (int)threadIdx.x;
    const int d = (blockIdx.x & 7) * 256 + tid;
    const int b0 = (int)(blockIdx.x >> 3) * RPB;

    const float RMIN = -5.0f, RMAX = 5.0f;

    // 25 coalesced loads (tab is L2/L3-resident: 200 KB); keep in registers.
    float sl[9], xk[9], yk[9];
#pragma unroll
    for (int k = 0; k < 9; ++k) sl[k] = tab[k * DDIM + d];
#pragma unroll
    for (int k = 1; k < 9; ++k) xk[k] = tab[(8 + k) * DDIM + d];
#pragma unroll
    for (int k = 1; k < 9; ++k) yk[k] = tab[(16 + k) * DDIM + d];

    const float log_s0 = __logf(sl[0]);
    const float log_sK = __logf(sl[8]);

    const float* xp = x_in + (size_t)b0 * DDIM + d;
    float* yp = y_out + (size_t)b0 * DDIM + d;

    float xv[RCHUNK], xn[RCHUNK];
#pragma unroll
    for (int r = 0; r < RCHUNK; ++r) xv[r] = xp[(size_t)r * DDIM];

#pragma unroll 1
    for (int rc = 0; rc < NCHUNK; ++rc) {
        // prefetch next chunk's x while computing this one
        if (rc + 1 < NCHUNK) {
#pragma unroll
            for (int r = 0; r < RCHUNK; ++r)
                xn[r] = xp[(size_t)((rc + 1) * RCHUNK + r) * DDIM];
        }

        float ldv[RCHUNK];
#pragma unroll
        for (int r = 0; r < RCHUNK; ++r) {
            const float x = xv[r];

            // chained select: after step j, state = values for bin>=j
            float x_k = RMIN, x_k1 = xk[1];
            float y_k = RMIN, y_k1 = yk[1];
            float dk = sl[0], dk1 = sl[1];
#pragma unroll
            for (int j = 1; j < 8; ++j) {
                const bool c = xk[j] <= x;
                x_k  = c ? xk[j]     : x_k;
                x_k1 = c ? xk[j + 1] : x_k1;
                y_k  = c ? yk[j]     : y_k;
                y_k1 = c ? yk[j + 1] : y_k1;
                dk   = c ? sl[j]     : dk;
                dk1  = c ? sl[j + 1] : dk1;
            }

            const float w = x_k1 - x_k;
            const float h = y_k1 - y_k;
            const float inv_w = fast_rcp(w);
            const float xi  = (x - x_k) * inv_w;
            const float s   = h * inv_w;
            const float xi1 = 1.0f - xi;
            const float xx  = xi * xi1;
            const float xi2 = xi * xi;

            const float num = fmaf(s, xi2, dk * xx);
            const float den = fmaf(fmaf(-2.0f, s, dk1 + dk), xx, s);
            const float inv_den = fast_rcp(den);

            const float y_sp = fmaf(h * num, inv_den, y_k);
            const float inner = fmaf(dk1, xi2, fmaf(s + s, xx, dk * (xi1 * xi1)));
            const float t = s * inv_den;

            const bool below = x <= RMIN;
            const bool above = x >= RMAX;
            float y  = below ? fmaf(x - RMIN, sl[0], RMIN)
                     : above ? fmaf(x - RMAX, sl[8], RMAX) : y_sp;
            float ld = below ? log_s0
                     : above ? log_sK : __logf(t * t * inner);

            // streaming store: keep y out of L2 (x and tab stay resident)
            __builtin_nontemporal_store(y, &yp[(size_t)(rc * RCHUNK + r) * DDIM]);
            ldv[r] = ld;
        }

        // 8 independent DPP reduce chains (VALU pipe), 1 atomic/row/wave
#pragma unroll
        for (int r = 0; r < RCHUNK; ++r) ldv[r] = wave_sum64(ldv[r]);
        if ((tid & 63) == 63) {
#pragma unroll
            for (int r = 0; r < RCHUNK; ++r)
                atomicAdd(&logdet[b0 + rc * RCHUNK + r], ldv[r]);
        }

#pragma unroll
        for (int r = 0; r < RCHUNK; ++r) xv[r] = xn[r];
    }
}

extern "C" void kernel_launch(void* const* d_in, const int* in_sizes, int n_in,
                              void* d_out, int out_size, void* d_ws, size_t ws_size,
                              hipStream_t stream) {
    const float* x = (const float*)d_in[0];
    const float* params = (const float*)d_in[1];
    float* out = (float*)d_out;
    float* y_out = out;                          // B*D floats
    float* logdet = out + (size_t)BROWS * DDIM;  // B floats
    float* tab = (float*)d_ws;                   // 25*D floats = 200 KiB

    normalize_kernel<<<DDIM / 128, 128, 0, stream>>>(params, tab, logdet);

    const int grid = 8 * (BROWS / RPB);          // 1024 blocks = one resident generation
    rqs_kernel<<<grid, 256, 0, stream>>>(x, tab, y_out, logdet);
}